// Round 6
// baseline (1123.165 us; speedup 1.0000x reference)
//
#include <hip/hip_runtime.h>

constexpr int C = 1024, H = 256, V = 10000, K = 32, B = 8, T = 256, K1K = 65;
constexpr int DB = 32;            // blocks per batch domain
constexpr int GSCAN = B * DB;     // 256
constexpr float LV = 9.210340371976184f;  // ln(10000)
constexpr unsigned SENT = 0x80000000u;    // -0.0f: u values are >0, sign bit never set

#define DEV static __device__ __forceinline__

typedef float f4 __attribute__((ext_vector_type(4)));

DEV void gstore(float* p, float v) {
  __hip_atomic_store((unsigned*)p, __float_as_uint(v), __ATOMIC_RELAXED, __HIP_MEMORY_SCOPE_AGENT);
}
DEV float gload(const float* p) {
  return __uint_as_float(__hip_atomic_load((unsigned*)p, __ATOMIC_RELAXED, __HIP_MEMORY_SCOPE_AGENT));
}

// ---------- fused pre-kernel ----------
// bid 0..15: sentinel-init pay; 16: start; 17..272: term MLP; 273..1296: trans rows
__global__ void __launch_bounds__(256) k_pre(
    const float* __restrict__ semb, const float* __restrict__ linW, const float* __restrict__ linb,
    const float* __restrict__ srW1, const float* __restrict__ srb1,
    const float* __restrict__ srW2, const float* __restrict__ srb2,
    const float* __restrict__ nse, const float* __restrict__ se,
    const float* __restrict__ pre, const float* __restrict__ trW1, const float* __restrict__ trb1,
    const float* __restrict__ trW2, const float* __restrict__ trb2,
    const float* __restrict__ band,
    float* __restrict__ pay, float* __restrict__ startv,
    float* __restrict__ ft, float* __restrict__ PT) {
  __shared__ float smem[2048];
  const int bid = blockIdx.x, tid = threadIdx.x;

  if (bid < 16) {  // sentinel-init all 4 payload buffers: 4*B*C dwords
    unsigned* p = (unsigned*)pay;
    #pragma unroll
    for (int k = 0; k < 8; ++k) p[bid * 2048 + k * 256 + tid] = SENT;
    return;
  }

  if (bid == 16) {  // start vector: MLP + log_softmax over C
    float* sa = smem;        // 256
    float* fx = smem + 256;  // 256
    float* hh = smem + 512;  // 256
    float* sl = smem + 768;  // 1024
    float* red = smem + 1792;
    sa[tid] = semb[tid];
    __syncthreads();
    float acc = linb[tid];
    for (int h = 0; h < H; ++h) acc += sa[h] * linW[tid * H + h];
    fx[tid] = acc;
    __syncthreads();
    for (int l = 0; l < 2; ++l) {
      float a1 = srb1[l * H + tid];
      const float* w1 = srW1 + (size_t)l * H * H + (size_t)tid * H;
      for (int h = 0; h < H; ++h) a1 += fx[h] * w1[h];
      hh[tid] = fmaxf(a1, 0.f);
      __syncthreads();
      float a2 = srb2[l * H + tid];
      const float* w2 = srW2 + (size_t)l * H * H + (size_t)tid * H;
      for (int h = 0; h < H; ++h) a2 += hh[h] * w2[h];
      __syncthreads();
      fx[tid] += fmaxf(a2, 0.f);
      __syncthreads();
    }
    for (int q = 0; q < 4; ++q) {
      int c = q * 256 + tid;
      const float* nr = nse + (size_t)c * H;
      float s = 0.f;
      for (int h = 0; h < H; ++h) s += fx[h] * nr[h];
      sl[c] = s;
    }
    __syncthreads();
    float m = -__builtin_inff();
    for (int q = 0; q < 4; ++q) m = fmaxf(m, sl[q * 256 + tid]);
    red[tid] = m; __syncthreads();
    for (int off = 128; off > 0; off >>= 1) { if (tid < off) red[tid] = fmaxf(red[tid], red[tid + off]); __syncthreads(); }
    m = red[0]; __syncthreads();
    float s = 0.f;
    for (int q = 0; q < 4; ++q) s += __expf(sl[q * 256 + tid] - m);
    red[tid] = s; __syncthreads();
    for (int off = 128; off > 0; off >>= 1) { if (tid < off) red[tid] += red[tid + off]; __syncthreads(); }
    float lse = m + __logf(red[0]);
    for (int q = 0; q < 4; ++q) { int c = q * 256 + tid; startv[c] = sl[c] - lse; }
    return;
  }

  if (bid < 273) {  // terminal MLP, 4 rows/block, f4 weight loads
    float (*x)[H] = (float(*)[H])smem;
    float (*hh)[H] = (float(*)[H])(smem + 1024);
    int r0 = (bid - 17) * 4;
    for (int r = 0; r < 4; ++r) x[r][tid] = pre[(size_t)(r0 + r) * H + tid];
    __syncthreads();
    for (int l = 0; l < 2; ++l) {
      {
        const f4* w1 = (const f4*)(trW1 + (size_t)l * H * H + (size_t)tid * H);
        f4 p0 = {0.f, 0.f, 0.f, 0.f}, p1 = p0, p2 = p0, p3 = p0;
        #pragma unroll 8
        for (int h4 = 0; h4 < H / 4; ++h4) {
          f4 w = w1[h4];
          p0 += w * *(const f4*)&x[0][h4 * 4];
          p1 += w * *(const f4*)&x[1][h4 * 4];
          p2 += w * *(const f4*)&x[2][h4 * 4];
          p3 += w * *(const f4*)&x[3][h4 * 4];
        }
        float bb = trb1[l * H + tid];
        hh[0][tid] = fmaxf(p0.x + p0.y + p0.z + p0.w + bb, 0.f);
        hh[1][tid] = fmaxf(p1.x + p1.y + p1.z + p1.w + bb, 0.f);
        hh[2][tid] = fmaxf(p2.x + p2.y + p2.z + p2.w + bb, 0.f);
        hh[3][tid] = fmaxf(p3.x + p3.y + p3.z + p3.w + bb, 0.f);
      }
      __syncthreads();
      {
        const f4* w2 = (const f4*)(trW2 + (size_t)l * H * H + (size_t)tid * H);
        f4 q0 = {0.f, 0.f, 0.f, 0.f}, q1 = q0, q2 = q0, q3 = q0;
        #pragma unroll 8
        for (int h4 = 0; h4 < H / 4; ++h4) {
          f4 w = w2[h4];
          q0 += w * *(const f4*)&hh[0][h4 * 4];
          q1 += w * *(const f4*)&hh[1][h4 * 4];
          q2 += w * *(const f4*)&hh[2][h4 * 4];
          q3 += w * *(const f4*)&hh[3][h4 * 4];
        }
        float bb = trb2[l * H + tid];
        __syncthreads();
        x[0][tid] += fmaxf(q0.x + q0.y + q0.z + q0.w + bb, 0.f);
        x[1][tid] += fmaxf(q1.x + q1.y + q1.z + q1.w + bb, 0.f);
        x[2][tid] += fmaxf(q2.x + q2.y + q2.z + q2.w + bb, 0.f);
        x[3][tid] += fmaxf(q3.x + q3.y + q3.z + q3.w + bb, 0.f);
      }
      __syncthreads();
    }
    for (int r = 0; r < 4; ++r) ft[(size_t)(r0 + r) * H + tid] = x[r][tid];
    return;
  }

  // transition row i: PT[j][i] = softmax_j(se_i . nse_j + band)
  {
    float* sv = smem;         // 256
    float* sl = smem + 256;   // 1024
    float* rr = smem + 1280;  // 256
    int i = bid - 273;
    sv[tid] = se[(size_t)i * H + tid];
    __syncthreads();
    #pragma unroll 1
    for (int jq = 0; jq < 4; ++jq) {
      int j = jq * 256 + tid;
      const float4* nr = (const float4*)(nse + (size_t)j * H);
      float acc = 0.f;
      #pragma unroll 8
      for (int h4 = 0; h4 < H / 4; ++h4) {
        float4 nv = nr[h4];
        float4 s4 = *(const float4*)&sv[h4 * 4];
        acc += s4.x * nv.x + s4.y * nv.y + s4.z * nv.z + s4.w * nv.w;
      }
      sl[j] = acc;
    }
    __syncthreads();
    if (tid < K1K) {
      int col = i + tid - K;
      if (col >= 0 && col < C) sl[col] += band[(size_t)i * K1K + tid];
    }
    __syncthreads();
    float m = -__builtin_inff();
    for (int q = 0; q < 4; ++q) m = fmaxf(m, sl[q * 256 + tid]);
    rr[tid] = m; __syncthreads();
    for (int off = 128; off > 0; off >>= 1) { if (tid < off) rr[tid] = fmaxf(rr[tid], rr[tid + off]); __syncthreads(); }
    m = rr[0]; __syncthreads();
    float e[4]; float s = 0.f;
    for (int q = 0; q < 4; ++q) { e[q] = __expf(sl[q * 256 + tid] - m); s += e[q]; }
    rr[tid] = s; __syncthreads();
    for (int off = 128; off > 0; off >>= 1) { if (tid < off) rr[tid] += rr[tid + off]; __syncthreads(); }
    float inv = 1.f / rr[0];
    for (int q = 0; q < 4; ++q) {
      int j = q * 256 + tid;
      PT[(size_t)j * C + i] = e[q] * inv;  // transposed store; coalesced preload in k_scan
    }
  }
}

// ---------- emission denominators (TJ=32: halves uncoalesced term transactions) ----------
__global__ void __launch_bounds__(256) k_denom_part(
    const float* __restrict__ ft, const float* __restrict__ term, float* __restrict__ dpart) {
  constexpr int TJ = 32, VC = V / 8;
  __shared__ float shm[TJ * 4], shs[TJ * 4];
  int tid = threadIdx.x, lane = tid & 63, w = tid >> 6;
  int jg = blockIdx.x >> 3, vc = blockIdx.x & 7;
  const float4* fb = (const float4*)(ft + (size_t)jg * TJ * H);
  float rm[TJ], rs[TJ];
  #pragma unroll
  for (int r = 0; r < TJ; ++r) { rm[r] = -__builtin_inff(); rs[r] = 0.f; }
  int v0 = vc * VC;
  for (int v = v0 + tid; v < v0 + VC; v += 256) {
    const float4* tr = (const float4*)(term + (size_t)v * H);
    float acc[TJ];
    #pragma unroll
    for (int r = 0; r < TJ; ++r) acc[r] = 0.f;
    for (int h4 = 0; h4 < H / 4; ++h4) {
      float4 tv = tr[h4];
      #pragma unroll
      for (int r = 0; r < TJ; ++r) {
        float4 f = fb[r * (H / 4) + h4];
        acc[r] += tv.x * f.x + tv.y * f.y + tv.z * f.z + tv.w * f.w;
      }
    }
    #pragma unroll
    for (int r = 0; r < TJ; ++r) {
      float m2 = fmaxf(rm[r], acc[r]);
      rs[r] = rs[r] * __expf(rm[r] - m2) + __expf(acc[r] - m2);
      rm[r] = m2;
    }
  }
  #pragma unroll
  for (int r = 0; r < TJ; ++r) {
    float m = rm[r], s = rs[r];
    #pragma unroll
    for (int off = 32; off > 0; off >>= 1) {
      float mo = __shfl_xor(m, off), so = __shfl_xor(s, off);
      float m2 = fmaxf(m, mo);
      s = s * __expf(m - m2) + so * __expf(mo - m2);
      m = m2;
    }
    if (lane == 0) { shm[r * 4 + w] = m; shs[r * 4 + w] = s; }
  }
  __syncthreads();
  if (tid < TJ) {
    float m = -__builtin_inff(), s = 0.f;
    for (int w2 = 0; w2 < 4; ++w2) {
      float mo = shm[tid * 4 + w2], so = shs[tid * 4 + w2];
      float m2 = fmaxf(m, mo);
      s = s * __expf(m - m2) + so * __expf(mo - m2);
      m = m2;
    }
    int j = jg * TJ + tid;
    dpart[(j * 8 + vc) * 2 + 0] = m;
    dpart[(j * 8 + vc) * 2 + 1] = s;
  }
}

__global__ void k_denom_comb(const float* __restrict__ dpart, float* __restrict__ denom) {
  int j = blockIdx.x * 256 + threadIdx.x;
  float m = -__builtin_inff(), s = 0.f;
  for (int vc = 0; vc < 8; ++vc) {
    float mo = dpart[(j * 8 + vc) * 2], so = dpart[(j * 8 + vc) * 2 + 1];
    float m2 = fmaxf(m, mo);
    s = s * __expf(m - m2) + so * __expf(mo - m2);
    m = m2;
  }
  denom[j] = m + __logf(s);
}

// ---------- eem[(t*B+b)*C + j] = exp(ft[j].term[tok] - denom[j] + LV) ----------
__global__ void __launch_bounds__(256) k_eemit(
    const int* __restrict__ text, const float* __restrict__ ft,
    const float* __restrict__ denom, const float* __restrict__ term,
    float* __restrict__ eem) {
  int tid = threadIdx.x;
  int n0 = blockIdx.x * 8;
  const float4* trow[8];
  #pragma unroll
  for (int r = 0; r < 8; ++r) {
    int n = n0 + r;
    int tok = text[(n & 7) * T + (n >> 3)];  // text[b*T + t], n = t*B+b
    trow[r] = (const float4*)(term + (size_t)tok * H);
  }
  for (int q = 0; q < 4; ++q) {
    int j = q * 256 + tid;
    const float4* fr = (const float4*)(ft + (size_t)j * H);
    float acc[8];
    #pragma unroll
    for (int r = 0; r < 8; ++r) acc[r] = 0.f;
    for (int h4 = 0; h4 < H / 4; ++h4) {
      float4 f = fr[h4];
      #pragma unroll
      for (int r = 0; r < 8; ++r) {
        float4 tv = trow[r][h4];
        acc[r] += f.x * tv.x + f.y * tv.y + f.z * tv.z + f.w * tv.w;
      }
    }
    float dj = denom[j];
    #pragma unroll
    for (int r = 0; r < 8; ++r) eem[(size_t)(n0 + r) * C + j] = __expf(acc[r] - dj + LV);
  }
}

// ---------- persistent linear-space scan: sentinel-polled payload, no flags ----------
// 256 blocks = 8 batches x 32 blocks. Thread (jloc=tid>>3, s=tid&7): owns
// PT[myj][s*128..+128) pinned in 128 VGPRs. 4 rotating payload buffers pay[p][B][C];
// consumers poll their own f4 until all sign bits clear (u > 0 always).
__global__ void __launch_bounds__(256, 1) k_scan(
    const float* __restrict__ PT, const float* __restrict__ eem,
    const float* __restrict__ startv, float* __restrict__ pay,
    float* __restrict__ umax, float* __restrict__ out) {
  __shared__ __align__(16) float us[8 * 132];  // phys(i) = (i>>7)*132 + (i&127)
  __shared__ float wv[32];
  __shared__ float fred[256];
  const int tid = threadIdx.x, bid = blockIdx.x;
  const int b = bid & 7, blk = bid >> 3;
  const int jloc = tid >> 3, s = tid & 7;
  const int myj = blk * 32 + jloc;
  const bool owner = (s == 0);

  // preload P slice and PIN in VGPRs (round-5 asm showed compiler re-loading it per step)
  f4 pv[32];
  {
    const f4* prow = (const f4*)(PT + (size_t)myj * C + s * 128);
    #pragma unroll
    for (int k4 = 0; k4 < 32; ++k4) pv[k4] = prow[k4];
    #pragma unroll
    for (int k4 = 0; k4 < 32; ++k4) asm volatile("" : "+v"(pv[k4]));
  }

  float Sacc = 0.f;

  // publish u_0 into buf 0 (buffers pre-sentineled by k_pre)
  if (owner) {
    float u0 = __expf(startv[myj]) * eem[(size_t)b * C + myj];
    gstore(&pay[(size_t)b * C + myj], u0);
  }
  float em = owner ? eem[((size_t)B + b) * C + myj] : 0.f;  // prefetch t=1

  const int pi = tid * 4;
  for (int t = 1; t < T; ++t) {
    // poll+stage u_{t-1} from buf (t-1)&3 (sentinel poll, backoff to limit L3 congestion)
    {
      const float* src = pay + (size_t)((t - 1) & 3) * (B * C) + (size_t)b * C + pi;
      f4 r;
      for (;;) {
        asm volatile("global_load_dwordx4 %0, %1, off sc0 sc1\n\ts_waitcnt vmcnt(0)"
                     : "=v"(r) : "v"(src) : "memory");
        unsigned bits = __float_as_uint(r.x) | __float_as_uint(r.y) |
                        __float_as_uint(r.z) | __float_as_uint(r.w);
        if (!(bits & 0x80000000u)) break;
        __builtin_amdgcn_s_sleep(1);
      }
      int ph = (pi >> 7) * 132 + (pi & 127);
      *(f4*)&us[ph] = r;
    }
    __syncthreads();

    // sentinel-clear my block's chunk in buf (t+1)&3 (holds u_{t-3}: consumed by all,
    // since observing u_{t-1} complete implies everyone finished reading u_{t-2})
    if (tid < 8) {
      float* dst = pay + (size_t)((t + 1) & 3) * (B * C) + (size_t)b * C + blk * 32 + tid * 4;
      f4 sn;
      sn.x = sn.y = sn.z = sn.w = __uint_as_float(SENT);
      asm volatile("global_store_dwordx4 %0, %1, off sc0 sc1" :: "v"(dst), "v"(sn) : "memory");
    }

    // rescale factor (umax slot written at step t-1, visible since we consumed u_{t-1})
    float imt = 1.f;
    if (owner && (t & 7) == 1 && t > 1) {
      float m = gload(&umax[((t - 1) >> 3) * 8 + b]);
      imt = 1.f / m;
      Sacc += __logf(m);
    }

    // dot: acc = sum_i u[i] * P[i][myj] over my 128-i slice, reduce over 8 s-lanes
    float acc = 0.f;
    {
      const int ubo = s * 132;
      #pragma unroll
      for (int k4 = 0; k4 < 32; ++k4) {
        f4 p = pv[k4];
        f4 x = *(const f4*)&us[ubo + k4 * 4];
        acc += p.x * x.x + p.y * x.y + p.z * x.z + p.w * x.w;
      }
    }
    acc += __shfl_xor(acc, 1);
    acc += __shfl_xor(acc, 2);
    acc += __shfl_xor(acc, 4);

    float val = 0.f;
    if (owner) {
      val = acc * imt * em;
      if (blk == 0) wv[jloc] = val;
    }
    // drain clears (wave0 issued them) so they are globally visible before ANY publish
    if (tid < 8) asm volatile("s_waitcnt vmcnt(0)" ::: "memory");
    __syncthreads();

    // sample-max: tid0 (blk0) orders umax before ITS OWN publish; consumers accept u_t
    // only when ALL values present, so umax is visible before any consumer reads it
    if (blk == 0 && (t & 7) == 0 && tid == 0) {
      float m = wv[0];
      #pragma unroll
      for (int j2 = 1; j2 < 32; ++j2) m = fmaxf(m, wv[j2]);
      gstore(&umax[(t >> 3) * 8 + b], m);
      asm volatile("s_waitcnt vmcnt(0)" ::: "memory");
    }
    if (owner) gstore(&pay[(size_t)(t & 3) * (B * C) + (size_t)b * C + myj], val);
    if (owner && t + 1 < T) em = eem[((size_t)(t + 1) * B + b) * C + myj];  // overlap next wait
  }

  // final: block 0 of each batch polls u_{T-1} and reduces
  if (blk == 0) {
    {
      const float* src = pay + (size_t)((T - 1) & 3) * (B * C) + (size_t)b * C + pi;
      f4 r;
      for (;;) {
        asm volatile("global_load_dwordx4 %0, %1, off sc0 sc1\n\ts_waitcnt vmcnt(0)"
                     : "=v"(r) : "v"(src) : "memory");
        unsigned bits = __float_as_uint(r.x) | __float_as_uint(r.y) |
                        __float_as_uint(r.z) | __float_as_uint(r.w);
        if (!(bits & 0x80000000u)) break;
        __builtin_amdgcn_s_sleep(1);
      }
      fred[tid] = r.x + r.y + r.z + r.w;
    }
    __syncthreads();
    for (int off = 128; off > 0; off >>= 1) {
      if (tid < off) fred[tid] += fred[tid + off];
      __syncthreads();
    }
    if (tid == 0) out[b] = -(float)T * LV + Sacc + __logf(fred[0]);
  }
}

extern "C" void kernel_launch(void* const* d_in, const int* in_sizes, int n_in,
                              void* d_out, int out_size, void* d_ws, size_t ws_size,
                              hipStream_t stream) {
  const int*   text  = (const int*)  d_in[0];
  const float* semb  = (const float*)d_in[1];
  const float* slinW = (const float*)d_in[2];
  const float* slinb = (const float*)d_in[3];
  const float* srW1  = (const float*)d_in[4];
  const float* srb1  = (const float*)d_in[5];
  const float* srW2  = (const float*)d_in[6];
  const float* srb2  = (const float*)d_in[7];
  const float* stemb = (const float*)d_in[8];
  const float* nse   = (const float*)d_in[9];
  const float* pre   = (const float*)d_in[10];
  const float* trW1  = (const float*)d_in[11];
  const float* trb1  = (const float*)d_in[12];
  const float* trW2  = (const float*)d_in[13];
  const float* trb2  = (const float*)d_in[14];
  const float* term  = (const float*)d_in[15];
  const float* band  = (const float*)d_in[16];

  float* ws     = (float*)d_ws;
  float* PT     = ws;                          // C*C (transposed P)
  float* eem    = PT + (size_t)C * C;          // T*B*C
  float* pay    = eem + (size_t)T * B * C;     // 4*B*C (4 rotating sentinel buffers)
  float* ftb    = pay + 4 * B * C;             // C*H
  float* startv = ftb + (size_t)C * H;         // C
  float* denom  = startv + C;                  // C
  float* dpart  = denom + C;                   // C*16
  float* umax   = dpart + C * 16;              // 32*8

  k_pre<<<1297, 256, 0, stream>>>(semb, slinW, slinb, srW1, srb1, srW2, srb2,
                                  nse, stemb, pre, trW1, trb1, trW2, trb2, band,
                                  pay, startv, ftb, PT);
  k_denom_part<<<(C / 32) * 8, 256, 0, stream>>>(ftb, term, dpart);
  k_denom_comb<<<C / 256, 256, 0, stream>>>(dpart, denom);
  k_eemit<<<(T * B) / 8, 256, 0, stream>>>(text, ftb, denom, term, eem);
  k_scan<<<GSCAN, 256, 0, stream>>>(PT, eem, startv, pay, umax, (float*)d_out);
}

// Round 7
// 913.876 us; speedup vs baseline: 1.2290x; 1.2290x over previous
//
#include <hip/hip_runtime.h>

constexpr int C = 1024, H = 256, V = 10000, K = 32, B = 8, T = 256, K1K = 65;
constexpr int DB = 32;            // blocks per batch domain
constexpr int GSCAN = B * DB;     // 256
constexpr float LV = 9.210340371976184f;  // ln(10000)
constexpr unsigned SENT = 0x80000000u;    // -0.0f: u values are >0, sign bit never set

#define DEV static __device__ __forceinline__

typedef float f4 __attribute__((ext_vector_type(4)));

DEV void gstore(float* p, float v) {
  __hip_atomic_store((unsigned*)p, __float_as_uint(v), __ATOMIC_RELAXED, __HIP_MEMORY_SCOPE_AGENT);
}
DEV float gload(const float* p) {
  return __uint_as_float(__hip_atomic_load((unsigned*)p, __ATOMIC_RELAXED, __HIP_MEMORY_SCOPE_AGENT));
}

// ---------- fused pre-kernel ----------
// bid 0..15: sentinel-init pay; 16: start; 17..272: term MLP; 273..1296: trans rows
__global__ void __launch_bounds__(256) k_pre(
    const float* __restrict__ semb, const float* __restrict__ linW, const float* __restrict__ linb,
    const float* __restrict__ srW1, const float* __restrict__ srb1,
    const float* __restrict__ srW2, const float* __restrict__ srb2,
    const float* __restrict__ nse, const float* __restrict__ se,
    const float* __restrict__ pre, const float* __restrict__ trW1, const float* __restrict__ trb1,
    const float* __restrict__ trW2, const float* __restrict__ trb2,
    const float* __restrict__ band,
    float* __restrict__ pay, float* __restrict__ startv,
    float* __restrict__ ft, float* __restrict__ PT) {
  __shared__ float smem[2048];
  const int bid = blockIdx.x, tid = threadIdx.x;

  if (bid < 16) {  // sentinel-init all 4 payload buffers: 4*B*C dwords
    unsigned* p = (unsigned*)pay;
    #pragma unroll
    for (int k = 0; k < 8; ++k) p[bid * 2048 + k * 256 + tid] = SENT;
    return;
  }

  if (bid == 16) {  // start vector: MLP + log_softmax over C
    float* sa = smem;        // 256
    float* fx = smem + 256;  // 256
    float* hh = smem + 512;  // 256
    float* sl = smem + 768;  // 1024
    float* red = smem + 1792;
    sa[tid] = semb[tid];
    __syncthreads();
    float acc = linb[tid];
    for (int h = 0; h < H; ++h) acc += sa[h] * linW[tid * H + h];
    fx[tid] = acc;
    __syncthreads();
    for (int l = 0; l < 2; ++l) {
      float a1 = srb1[l * H + tid];
      const float* w1 = srW1 + (size_t)l * H * H + (size_t)tid * H;
      for (int h = 0; h < H; ++h) a1 += fx[h] * w1[h];
      hh[tid] = fmaxf(a1, 0.f);
      __syncthreads();
      float a2 = srb2[l * H + tid];
      const float* w2 = srW2 + (size_t)l * H * H + (size_t)tid * H;
      for (int h = 0; h < H; ++h) a2 += hh[h] * w2[h];
      __syncthreads();
      fx[tid] += fmaxf(a2, 0.f);
      __syncthreads();
    }
    for (int q = 0; q < 4; ++q) {
      int c = q * 256 + tid;
      const float* nr = nse + (size_t)c * H;
      float s = 0.f;
      for (int h = 0; h < H; ++h) s += fx[h] * nr[h];
      sl[c] = s;
    }
    __syncthreads();
    float m = -__builtin_inff();
    for (int q = 0; q < 4; ++q) m = fmaxf(m, sl[q * 256 + tid]);
    red[tid] = m; __syncthreads();
    for (int off = 128; off > 0; off >>= 1) { if (tid < off) red[tid] = fmaxf(red[tid], red[tid + off]); __syncthreads(); }
    m = red[0]; __syncthreads();
    float s = 0.f;
    for (int q = 0; q < 4; ++q) s += __expf(sl[q * 256 + tid] - m);
    red[tid] = s; __syncthreads();
    for (int off = 128; off > 0; off >>= 1) { if (tid < off) red[tid] += red[tid + off]; __syncthreads(); }
    float lse = m + __logf(red[0]);
    for (int q = 0; q < 4; ++q) { int c = q * 256 + tid; startv[c] = sl[c] - lse; }
    return;
  }

  if (bid < 273) {  // terminal MLP, 4 rows/block, f4 weight loads
    float (*x)[H] = (float(*)[H])smem;
    float (*hh)[H] = (float(*)[H])(smem + 1024);
    int r0 = (bid - 17) * 4;
    for (int r = 0; r < 4; ++r) x[r][tid] = pre[(size_t)(r0 + r) * H + tid];
    __syncthreads();
    for (int l = 0; l < 2; ++l) {
      {
        const f4* w1 = (const f4*)(trW1 + (size_t)l * H * H + (size_t)tid * H);
        f4 p0 = {0.f, 0.f, 0.f, 0.f}, p1 = p0, p2 = p0, p3 = p0;
        #pragma unroll 8
        for (int h4 = 0; h4 < H / 4; ++h4) {
          f4 w = w1[h4];
          p0 += w * *(const f4*)&x[0][h4 * 4];
          p1 += w * *(const f4*)&x[1][h4 * 4];
          p2 += w * *(const f4*)&x[2][h4 * 4];
          p3 += w * *(const f4*)&x[3][h4 * 4];
        }
        float bb = trb1[l * H + tid];
        hh[0][tid] = fmaxf(p0.x + p0.y + p0.z + p0.w + bb, 0.f);
        hh[1][tid] = fmaxf(p1.x + p1.y + p1.z + p1.w + bb, 0.f);
        hh[2][tid] = fmaxf(p2.x + p2.y + p2.z + p2.w + bb, 0.f);
        hh[3][tid] = fmaxf(p3.x + p3.y + p3.z + p3.w + bb, 0.f);
      }
      __syncthreads();
      {
        const f4* w2 = (const f4*)(trW2 + (size_t)l * H * H + (size_t)tid * H);
        f4 q0 = {0.f, 0.f, 0.f, 0.f}, q1 = q0, q2 = q0, q3 = q0;
        #pragma unroll 8
        for (int h4 = 0; h4 < H / 4; ++h4) {
          f4 w = w2[h4];
          q0 += w * *(const f4*)&hh[0][h4 * 4];
          q1 += w * *(const f4*)&hh[1][h4 * 4];
          q2 += w * *(const f4*)&hh[2][h4 * 4];
          q3 += w * *(const f4*)&hh[3][h4 * 4];
        }
        float bb = trb2[l * H + tid];
        __syncthreads();
        x[0][tid] += fmaxf(q0.x + q0.y + q0.z + q0.w + bb, 0.f);
        x[1][tid] += fmaxf(q1.x + q1.y + q1.z + q1.w + bb, 0.f);
        x[2][tid] += fmaxf(q2.x + q2.y + q2.z + q2.w + bb, 0.f);
        x[3][tid] += fmaxf(q3.x + q3.y + q3.z + q3.w + bb, 0.f);
      }
      __syncthreads();
    }
    for (int r = 0; r < 4; ++r) ft[(size_t)(r0 + r) * H + tid] = x[r][tid];
    return;
  }

  // transition row i: PT[j][i] = softmax_j(se_i . nse_j + band)
  {
    float* sv = smem;         // 256
    float* sl = smem + 256;   // 1024
    float* rr = smem + 1280;  // 256
    int i = bid - 273;
    sv[tid] = se[(size_t)i * H + tid];
    __syncthreads();
    #pragma unroll 1
    for (int jq = 0; jq < 4; ++jq) {
      int j = jq * 256 + tid;
      const float4* nr = (const float4*)(nse + (size_t)j * H);
      float acc = 0.f;
      #pragma unroll 8
      for (int h4 = 0; h4 < H / 4; ++h4) {
        float4 nv = nr[h4];
        float4 s4 = *(const float4*)&sv[h4 * 4];
        acc += s4.x * nv.x + s4.y * nv.y + s4.z * nv.z + s4.w * nv.w;
      }
      sl[j] = acc;
    }
    __syncthreads();
    if (tid < K1K) {
      int col = i + tid - K;
      if (col >= 0 && col < C) sl[col] += band[(size_t)i * K1K + tid];
    }
    __syncthreads();
    float m = -__builtin_inff();
    for (int q = 0; q < 4; ++q) m = fmaxf(m, sl[q * 256 + tid]);
    rr[tid] = m; __syncthreads();
    for (int off = 128; off > 0; off >>= 1) { if (tid < off) rr[tid] = fmaxf(rr[tid], rr[tid + off]); __syncthreads(); }
    m = rr[0]; __syncthreads();
    float e[4]; float s = 0.f;
    for (int q = 0; q < 4; ++q) { e[q] = __expf(sl[q * 256 + tid] - m); s += e[q]; }
    rr[tid] = s; __syncthreads();
    for (int off = 128; off > 0; off >>= 1) { if (tid < off) rr[tid] += rr[tid + off]; __syncthreads(); }
    float inv = 1.f / rr[0];
    for (int q = 0; q < 4; ++q) {
      int j = q * 256 + tid;
      PT[(size_t)j * C + i] = e[q] * inv;  // transposed store; coalesced preload in k_scan
    }
  }
}

// ---------- emission denominators: SUM-ONLY partials (logits ~ O(0.1), no max needed) ----------
__global__ void __launch_bounds__(256) k_denom_part(
    const float* __restrict__ ft, const float* __restrict__ term, float* __restrict__ dpart) {
  constexpr int TJ = 16, VC = V / 8;
  __shared__ float shs[TJ * 4];
  int tid = threadIdx.x, lane = tid & 63, w = tid >> 6;
  int jg = blockIdx.x >> 3, vc = blockIdx.x & 7;
  const float4* fb = (const float4*)(ft + (size_t)jg * TJ * H);
  float rs[TJ];
  #pragma unroll
  for (int r = 0; r < TJ; ++r) rs[r] = 0.f;
  int v0 = vc * VC;
  for (int v = v0 + tid; v < v0 + VC; v += 256) {
    const float4* tr = (const float4*)(term + (size_t)v * H);
    float acc[TJ];
    #pragma unroll
    for (int r = 0; r < TJ; ++r) acc[r] = 0.f;
    for (int h4 = 0; h4 < H / 4; ++h4) {
      float4 tv = tr[h4];
      #pragma unroll
      for (int r = 0; r < TJ; ++r) {
        float4 f = fb[r * (H / 4) + h4];
        acc[r] += tv.x * f.x + tv.y * f.y + tv.z * f.z + tv.w * f.w;
      }
    }
    #pragma unroll
    for (int r = 0; r < TJ; ++r) rs[r] += __expf(acc[r]);
  }
  #pragma unroll
  for (int r = 0; r < TJ; ++r) {
    float s = rs[r];
    #pragma unroll
    for (int off = 32; off > 0; off >>= 1) s += __shfl_xor(s, off);
    if (lane == 0) shs[r * 4 + w] = s;
  }
  __syncthreads();
  if (tid < TJ) {
    float s = shs[tid * 4] + shs[tid * 4 + 1] + shs[tid * 4 + 2] + shs[tid * 4 + 3];
    dpart[(jg * TJ + tid) * 8 + vc] = s;
  }
}

// ---------- eem[(t*B+b)*C + j] = exp(ft[j].term[tok] - log(sum dpart[j]) + LV) ----------
__global__ void __launch_bounds__(256) k_eemit(
    const int* __restrict__ text, const float* __restrict__ ft,
    const float* __restrict__ dpart, const float* __restrict__ term,
    float* __restrict__ eem) {
  int tid = threadIdx.x;
  int n0 = blockIdx.x * 8;
  const float4* trow[8];
  #pragma unroll
  for (int r = 0; r < 8; ++r) {
    int n = n0 + r;
    int tok = text[(n & 7) * T + (n >> 3)];  // text[b*T + t], n = t*B+b
    trow[r] = (const float4*)(term + (size_t)tok * H);
  }
  for (int q = 0; q < 4; ++q) {
    int j = q * 256 + tid;
    const float4* fr = (const float4*)(ft + (size_t)j * H);
    float acc[8];
    #pragma unroll
    for (int r = 0; r < 8; ++r) acc[r] = 0.f;
    for (int h4 = 0; h4 < H / 4; ++h4) {
      float4 f = fr[h4];
      #pragma unroll
      for (int r = 0; r < 8; ++r) {
        float4 tv = trow[r][h4];
        acc[r] += f.x * tv.x + f.y * tv.y + f.z * tv.z + f.w * tv.w;
      }
    }
    f4 d0 = *(const f4*)&dpart[j * 8];
    f4 d1 = *(const f4*)&dpart[j * 8 + 4];
    float dj = __logf(d0.x + d0.y + d0.z + d0.w + d1.x + d1.y + d1.z + d1.w);
    #pragma unroll
    for (int r = 0; r < 8; ++r) eem[(size_t)(n0 + r) * C + j] = __expf(acc[r] - dj + LV);
  }
}

// ---------- persistent linear-space scan: sentinel-polled payload ----------
// 256 blocks = 8 batches x 32 blocks. Thread (jloc=tid>>3, s=tid&7): owns
// PT[myj][s*128..+128) in 32 NAMED f4 regs, re-pinned every iteration (no remat).
#define PLOAD(k) f4 p##k = prow[k];
#define PDOT(k) { f4 x = *(const f4*)&us[ubo + (k) * 4]; \
  acc += p##k.x * x.x + p##k.y * x.y + p##k.z * x.z + p##k.w * x.w; }
#define PPIN8(a,b,c,d,e,f,g,h) asm volatile("" : "+v"(p##a), "+v"(p##b), "+v"(p##c), \
  "+v"(p##d), "+v"(p##e), "+v"(p##f), "+v"(p##g), "+v"(p##h));

__global__ void __launch_bounds__(256, 1) k_scan(
    const float* __restrict__ PT, const float* __restrict__ eem,
    const float* __restrict__ startv, float* __restrict__ pay,
    float* __restrict__ umax, float* __restrict__ out) {
  __shared__ __align__(16) float us[8 * 132];  // phys(i) = (i>>7)*132 + (i&127)
  __shared__ float wv[32];
  __shared__ float fred[256];
  const int tid = threadIdx.x, bid = blockIdx.x;
  const int b = bid & 7, blk = bid >> 3;
  const int jloc = tid >> 3, s = tid & 7;
  const int myj = blk * 32 + jloc;
  const bool owner = (s == 0);

  const f4* prow = (const f4*)(PT + (size_t)myj * C + s * 128);
  PLOAD(0) PLOAD(1) PLOAD(2) PLOAD(3) PLOAD(4) PLOAD(5) PLOAD(6) PLOAD(7)
  PLOAD(8) PLOAD(9) PLOAD(10) PLOAD(11) PLOAD(12) PLOAD(13) PLOAD(14) PLOAD(15)
  PLOAD(16) PLOAD(17) PLOAD(18) PLOAD(19) PLOAD(20) PLOAD(21) PLOAD(22) PLOAD(23)
  PLOAD(24) PLOAD(25) PLOAD(26) PLOAD(27) PLOAD(28) PLOAD(29) PLOAD(30) PLOAD(31)

  float Sacc = 0.f;

  // publish u_0 into buf 0 (buffers pre-sentineled by k_pre)
  if (owner) {
    float u0 = __expf(startv[myj]) * eem[(size_t)b * C + myj];
    gstore(&pay[(size_t)b * C + myj], u0);
  }
  float em = owner ? eem[((size_t)B + b) * C + myj] : 0.f;  // prefetch t=1

  const int pi = tid * 4;
  const int ph = (pi >> 7) * 132 + (pi & 127);
  const int ubo = s * 132;

  for (int t = 1; t < T; ++t) {
    // poll+stage u_{t-1} from buf (t-1)&3. The vmcnt(0) here also drains this
    // thread's sentinel-clears from the previous iteration (ordering for publish).
    {
      const float* src = pay + (size_t)((t - 1) & 3) * (B * C) + (size_t)b * C + pi;
      f4 r;
      for (;;) {
        asm volatile("global_load_dwordx4 %0, %1, off sc0 sc1\n\ts_waitcnt vmcnt(0)"
                     : "=v"(r) : "v"(src) : "memory");
        unsigned bits = __float_as_uint(r.x) | __float_as_uint(r.y) |
                        __float_as_uint(r.z) | __float_as_uint(r.w);
        if (!(bits & 0x80000000u)) break;
        __builtin_amdgcn_s_sleep(1);
      }
      *(f4*)&us[ph] = r;
    }
    __syncthreads();

    // rescale factor (umax slot written at step t-1, visible since u_{t-1} consumed)
    float imt = 1.f;
    if (owner && (t & 7) == 1 && t > 1) {
      float m = gload(&umax[((t - 1) >> 3) * 8 + b]);
      imt = 1.f / m;
      Sacc += __logf(m);
    }

    // re-pin P registers: makes them loop-carried-opaque so the compiler cannot
    // rematerialize the PT loads inside the loop (round-6 VGPR=92 showed it did)
    PPIN8(0,1,2,3,4,5,6,7) PPIN8(8,9,10,11,12,13,14,15)
    PPIN8(16,17,18,19,20,21,22,23) PPIN8(24,25,26,27,28,29,30,31)

    // dot over my 128-i slice, reduce over the 8 s-lanes of this j
    float acc = 0.f;
    PDOT(0) PDOT(1) PDOT(2) PDOT(3) PDOT(4) PDOT(5) PDOT(6) PDOT(7)
    PDOT(8) PDOT(9) PDOT(10) PDOT(11) PDOT(12) PDOT(13) PDOT(14) PDOT(15)
    PDOT(16) PDOT(17) PDOT(18) PDOT(19) PDOT(20) PDOT(21) PDOT(22) PDOT(23)
    PDOT(24) PDOT(25) PDOT(26) PDOT(27) PDOT(28) PDOT(29) PDOT(30) PDOT(31)
    acc += __shfl_xor(acc, 1);
    acc += __shfl_xor(acc, 2);
    acc += __shfl_xor(acc, 4);

    float val = 0.f;
    if (owner) val = acc * imt * em;

    // sample-max every 8 steps (blk0 only): ordered before tid0's own publish;
    // consumers gate on FULL u_t (incl. tid0's j=0), so umax is visible when read
    if (blk == 0 && (t & 7) == 0) {
      if (owner) wv[jloc] = val;
      __syncthreads();
      if (tid == 0) {
        float m = wv[0];
        #pragma unroll
        for (int j2 = 1; j2 < 32; ++j2) m = fmaxf(m, wv[j2]);
        gstore(&umax[(t >> 3) * 8 + b], m);
        asm volatile("s_waitcnt vmcnt(0)" ::: "memory");
      }
    }

    // publish u_t
    if (owner) gstore(&pay[(size_t)(t & 3) * (B * C) + (size_t)b * C + myj], val);

    // sentinel-clear buf (t+1)&3 (holds dead u_{t-3}); completion enforced by this
    // thread's next-iteration poll vmcnt(0), which precedes the next publish barrier
    if (tid < 8) {
      float* dst = pay + (size_t)((t + 1) & 3) * (B * C) + (size_t)b * C + blk * 32 + tid * 4;
      f4 sn;
      sn.x = sn.y = sn.z = sn.w = __uint_as_float(SENT);
      asm volatile("global_store_dwordx4 %0, %1, off sc0 sc1" :: "v"(dst), "v"(sn) : "memory");
    }
    if (owner && t + 1 < T) em = eem[((size_t)(t + 1) * B + b) * C + myj];  // overlap next wait
  }

  // final: block 0 of each batch polls u_{T-1} and reduces
  if (blk == 0) {
    {
      const float* src = pay + (size_t)((T - 1) & 3) * (B * C) + (size_t)b * C + pi;
      f4 r;
      for (;;) {
        asm volatile("global_load_dwordx4 %0, %1, off sc0 sc1\n\ts_waitcnt vmcnt(0)"
                     : "=v"(r) : "v"(src) : "memory");
        unsigned bits = __float_as_uint(r.x) | __float_as_uint(r.y) |
                        __float_as_uint(r.z) | __float_as_uint(r.w);
        if (!(bits & 0x80000000u)) break;
        __builtin_amdgcn_s_sleep(1);
      }
      fred[tid] = r.x + r.y + r.z + r.w;
    }
    __syncthreads();
    for (int off = 128; off > 0; off >>= 1) {
      if (tid < off) fred[tid] += fred[tid + off];
      __syncthreads();
    }
    if (tid == 0) out[b] = -(float)T * LV + Sacc + __logf(fred[0]);
  }
}

extern "C" void kernel_launch(void* const* d_in, const int* in_sizes, int n_in,
                              void* d_out, int out_size, void* d_ws, size_t ws_size,
                              hipStream_t stream) {
  const int*   text  = (const int*)  d_in[0];
  const float* semb  = (const float*)d_in[1];
  const float* slinW = (const float*)d_in[2];
  const float* slinb = (const float*)d_in[3];
  const float* srW1  = (const float*)d_in[4];
  const float* srb1  = (const float*)d_in[5];
  const float* srW2  = (const float*)d_in[6];
  const float* srb2  = (const float*)d_in[7];
  const float* stemb = (const float*)d_in[8];
  const float* nse   = (const float*)d_in[9];
  const float* pre   = (const float*)d_in[10];
  const float* trW1  = (const float*)d_in[11];
  const float* trb1  = (const float*)d_in[12];
  const float* trW2  = (const float*)d_in[13];
  const float* trb2  = (const float*)d_in[14];
  const float* term  = (const float*)d_in[15];
  const float* band  = (const float*)d_in[16];

  float* ws     = (float*)d_ws;
  float* PT     = ws;                          // C*C (transposed P)
  float* eem    = PT + (size_t)C * C;          // T*B*C
  float* pay    = eem + (size_t)T * B * C;     // 4*B*C (4 rotating sentinel buffers)
  float* ftb    = pay + 4 * B * C;             // C*H
  float* startv = ftb + (size_t)C * H;         // C
  float* dpart  = startv + C;                  // C*8 (sum partials)
  float* umax   = dpart + C * 8;               // 32*8

  k_pre<<<1297, 256, 0, stream>>>(semb, slinW, slinb, srW1, srb1, srW2, srb2,
                                  nse, stemb, pre, trW1, trb1, trW2, trb2, band,
                                  pay, startv, ftb, PT);
  k_denom_part<<<(C / 16) * 8, 256, 0, stream>>>(ftb, term, dpart);
  k_eemit<<<(T * B) / 8, 256, 0, stream>>>(text, ftb, dpart, term, eem);
  k_scan<<<GSCAN, 256, 0, stream>>>(PT, eem, startv, pay, umax, (float*)d_out);
}

// Round 8
// 881.090 us; speedup vs baseline: 1.2747x; 1.0372x over previous
//
#include <hip/hip_runtime.h>

constexpr int C = 1024, H = 256, V = 10000, K = 32, B = 8, T = 256, K1K = 65;
constexpr int DB = 32;            // blocks per batch domain
constexpr int GSCAN = B * DB;     // 256
constexpr float LV = 9.210340371976184f;  // ln(10000)
constexpr unsigned SENT = 0x80000000u;    // -0.0f: u values are >0, sign bit never set

#define DEV static __device__ __forceinline__

typedef float f4 __attribute__((ext_vector_type(4)));

DEV void gstore(float* p, float v) {
  __hip_atomic_store((unsigned*)p, __float_as_uint(v), __ATOMIC_RELAXED, __HIP_MEMORY_SCOPE_AGENT);
}
DEV float gload(const float* p) {
  return __uint_as_float(__hip_atomic_load((unsigned*)p, __ATOMIC_RELAXED, __HIP_MEMORY_SCOPE_AGENT));
}

// ---------- fused pre-kernel ----------
// bid 0..15: sentinel-init pay; 16: start; 17..272: term MLP; 273..528: trans (4 rows each)
__global__ void __launch_bounds__(256) k_pre(
    const float* __restrict__ semb, const float* __restrict__ linW, const float* __restrict__ linb,
    const float* __restrict__ srW1, const float* __restrict__ srb1,
    const float* __restrict__ srW2, const float* __restrict__ srb2,
    const float* __restrict__ nse, const float* __restrict__ se,
    const float* __restrict__ pre, const float* __restrict__ trW1, const float* __restrict__ trb1,
    const float* __restrict__ trW2, const float* __restrict__ trb2,
    const float* __restrict__ band,
    float* __restrict__ pay, float* __restrict__ startv,
    float* __restrict__ ft, float* __restrict__ PT) {
  __shared__ float smem[5376];
  const int bid = blockIdx.x, tid = threadIdx.x;

  if (bid < 16) {  // sentinel-init all 4 payload buffers: 4*B*C dwords
    unsigned* p = (unsigned*)pay;
    #pragma unroll
    for (int k = 0; k < 8; ++k) p[bid * 2048 + k * 256 + tid] = SENT;
    return;
  }

  if (bid == 16) {  // start vector: MLP + log_softmax over C
    float* sa = smem;        // 256
    float* fx = smem + 256;  // 256
    float* hh = smem + 512;  // 256
    float* sl = smem + 768;  // 1024
    float* red = smem + 1792;
    sa[tid] = semb[tid];
    __syncthreads();
    float acc = linb[tid];
    for (int h = 0; h < H; ++h) acc += sa[h] * linW[tid * H + h];
    fx[tid] = acc;
    __syncthreads();
    for (int l = 0; l < 2; ++l) {
      float a1 = srb1[l * H + tid];
      const float* w1 = srW1 + (size_t)l * H * H + (size_t)tid * H;
      for (int h = 0; h < H; ++h) a1 += fx[h] * w1[h];
      hh[tid] = fmaxf(a1, 0.f);
      __syncthreads();
      float a2 = srb2[l * H + tid];
      const float* w2 = srW2 + (size_t)l * H * H + (size_t)tid * H;
      for (int h = 0; h < H; ++h) a2 += hh[h] * w2[h];
      __syncthreads();
      fx[tid] += fmaxf(a2, 0.f);
      __syncthreads();
    }
    for (int q = 0; q < 4; ++q) {
      int c = q * 256 + tid;
      const float* nr = nse + (size_t)c * H;
      float s = 0.f;
      for (int h = 0; h < H; ++h) s += fx[h] * nr[h];
      sl[c] = s;
    }
    __syncthreads();
    float m = -__builtin_inff();
    for (int q = 0; q < 4; ++q) m = fmaxf(m, sl[q * 256 + tid]);
    red[tid] = m; __syncthreads();
    for (int off = 128; off > 0; off >>= 1) { if (tid < off) red[tid] = fmaxf(red[tid], red[tid + off]); __syncthreads(); }
    m = red[0]; __syncthreads();
    float s = 0.f;
    for (int q = 0; q < 4; ++q) s += __expf(sl[q * 256 + tid] - m);
    red[tid] = s; __syncthreads();
    for (int off = 128; off > 0; off >>= 1) { if (tid < off) red[tid] += red[tid + off]; __syncthreads(); }
    float lse = m + __logf(red[0]);
    for (int q = 0; q < 4; ++q) { int c = q * 256 + tid; startv[c] = sl[c] - lse; }
    return;
  }

  if (bid < 273) {  // terminal MLP, 4 rows/block, f4 weight loads
    float (*x)[H] = (float(*)[H])smem;
    float (*hh)[H] = (float(*)[H])(smem + 1024);
    int r0 = (bid - 17) * 4;
    for (int r = 0; r < 4; ++r) x[r][tid] = pre[(size_t)(r0 + r) * H + tid];
    __syncthreads();
    for (int l = 0; l < 2; ++l) {
      {
        const f4* w1 = (const f4*)(trW1 + (size_t)l * H * H + (size_t)tid * H);
        f4 p0 = {0.f, 0.f, 0.f, 0.f}, p1 = p0, p2 = p0, p3 = p0;
        #pragma unroll 8
        for (int h4 = 0; h4 < H / 4; ++h4) {
          f4 w = w1[h4];
          p0 += w * *(const f4*)&x[0][h4 * 4];
          p1 += w * *(const f4*)&x[1][h4 * 4];
          p2 += w * *(const f4*)&x[2][h4 * 4];
          p3 += w * *(const f4*)&x[3][h4 * 4];
        }
        float bb = trb1[l * H + tid];
        hh[0][tid] = fmaxf(p0.x + p0.y + p0.z + p0.w + bb, 0.f);
        hh[1][tid] = fmaxf(p1.x + p1.y + p1.z + p1.w + bb, 0.f);
        hh[2][tid] = fmaxf(p2.x + p2.y + p2.z + p2.w + bb, 0.f);
        hh[3][tid] = fmaxf(p3.x + p3.y + p3.z + p3.w + bb, 0.f);
      }
      __syncthreads();
      {
        const f4* w2 = (const f4*)(trW2 + (size_t)l * H * H + (size_t)tid * H);
        f4 q0 = {0.f, 0.f, 0.f, 0.f}, q1 = q0, q2 = q0, q3 = q0;
        #pragma unroll 8
        for (int h4 = 0; h4 < H / 4; ++h4) {
          f4 w = w2[h4];
          q0 += w * *(const f4*)&hh[0][h4 * 4];
          q1 += w * *(const f4*)&hh[1][h4 * 4];
          q2 += w * *(const f4*)&hh[2][h4 * 4];
          q3 += w * *(const f4*)&hh[3][h4 * 4];
        }
        float bb = trb2[l * H + tid];
        __syncthreads();
        x[0][tid] += fmaxf(q0.x + q0.y + q0.z + q0.w + bb, 0.f);
        x[1][tid] += fmaxf(q1.x + q1.y + q1.z + q1.w + bb, 0.f);
        x[2][tid] += fmaxf(q2.x + q2.y + q2.z + q2.w + bb, 0.f);
        x[3][tid] += fmaxf(q3.x + q3.y + q3.z + q3.w + bb, 0.f);
      }
      __syncthreads();
    }
    for (int r = 0; r < 4; ++r) ft[(size_t)(r0 + r) * H + tid] = x[r][tid];
    return;
  }

  // transition: 4 rows per block. PT[j][i] = softmax_j(se_i . nse_j + band)
  {
    float* sv = smem;         // 4*256
    float* sl = smem + 1024;  // 4*1024
    float* rr = smem + 5120;  // 256
    int i0 = (bid - 273) * 4;
    for (int r = 0; r < 4; ++r) sv[r * 256 + tid] = se[(size_t)(i0 + r) * H + tid];
    __syncthreads();
    #pragma unroll 1
    for (int jq = 0; jq < 4; ++jq) {
      int j = jq * 256 + tid;
      const f4* nr = (const f4*)(nse + (size_t)j * H);
      float a0 = 0.f, a1 = 0.f, a2 = 0.f, a3 = 0.f;
      #pragma unroll 8
      for (int h4 = 0; h4 < H / 4; ++h4) {
        f4 nv = nr[h4];
        f4 s0 = *(const f4*)&sv[0 * 256 + h4 * 4];
        f4 s1 = *(const f4*)&sv[1 * 256 + h4 * 4];
        f4 s2 = *(const f4*)&sv[2 * 256 + h4 * 4];
        f4 s3 = *(const f4*)&sv[3 * 256 + h4 * 4];
        a0 += nv.x * s0.x + nv.y * s0.y + nv.z * s0.z + nv.w * s0.w;
        a1 += nv.x * s1.x + nv.y * s1.y + nv.z * s1.z + nv.w * s1.w;
        a2 += nv.x * s2.x + nv.y * s2.y + nv.z * s2.z + nv.w * s2.w;
        a3 += nv.x * s3.x + nv.y * s3.y + nv.z * s3.z + nv.w * s3.w;
      }
      sl[0 * 1024 + j] = a0; sl[1 * 1024 + j] = a1;
      sl[2 * 1024 + j] = a2; sl[3 * 1024 + j] = a3;
    }
    __syncthreads();
    if (tid < K1K) {
      #pragma unroll
      for (int r = 0; r < 4; ++r) {
        int col = i0 + r + tid - K;
        if (col >= 0 && col < C) sl[r * 1024 + col] += band[(size_t)(i0 + r) * K1K + tid];
      }
    }
    __syncthreads();
    #pragma unroll 1
    for (int r = 0; r < 4; ++r) {
      float* slr = sl + r * 1024;
      float m = -__builtin_inff();
      for (int q = 0; q < 4; ++q) m = fmaxf(m, slr[q * 256 + tid]);
      rr[tid] = m; __syncthreads();
      for (int off = 128; off > 0; off >>= 1) { if (tid < off) rr[tid] = fmaxf(rr[tid], rr[tid + off]); __syncthreads(); }
      m = rr[0]; __syncthreads();
      float e[4]; float s = 0.f;
      for (int q = 0; q < 4; ++q) { e[q] = __expf(slr[q * 256 + tid] - m); s += e[q]; }
      rr[tid] = s; __syncthreads();
      for (int off = 128; off > 0; off >>= 1) { if (tid < off) rr[tid] += rr[tid + off]; __syncthreads(); }
      float inv = 1.f / rr[0];
      for (int q = 0; q < 4; ++q) {
        int j = q * 256 + tid;
        PT[(size_t)j * C + i0 + r] = e[q] * inv;
      }
      __syncthreads();
    }
  }
}

// ---------- emission denominators: sum-only, v-unrolled x4 (VALU-bound) ----------
__global__ void __launch_bounds__(256) k_denom_part(
    const float* __restrict__ ft, const float* __restrict__ term, float* __restrict__ dpart) {
  constexpr int TJ = 16, VC = V / 8;  // 1250 = 4*256 + 226
  __shared__ float shs[TJ * 4];
  int tid = threadIdx.x, lane = tid & 63, w = tid >> 6;
  int jg = blockIdx.x >> 3, vc = blockIdx.x & 7;
  const f4* fb = (const f4*)(ft + (size_t)jg * TJ * H);
  float rs[TJ];
  #pragma unroll
  for (int r = 0; r < TJ; ++r) rs[r] = 0.f;
  int v0 = vc * VC;
  {  // main: 4 v-rows per thread, term f4s shared across 16 j
    const f4* t0 = (const f4*)(term + (size_t)(v0 + tid) * H);
    const f4* t1 = t0 + 256 * (H / 4);
    const f4* t2 = t1 + 256 * (H / 4);
    const f4* t3 = t2 + 256 * (H / 4);
    float a0[TJ], a1[TJ], a2[TJ], a3[TJ];
    #pragma unroll
    for (int r = 0; r < TJ; ++r) { a0[r] = 0.f; a1[r] = 0.f; a2[r] = 0.f; a3[r] = 0.f; }
    for (int h4 = 0; h4 < H / 4; ++h4) {
      f4 w0 = t0[h4], w1 = t1[h4], w2 = t2[h4], w3 = t3[h4];
      #pragma unroll
      for (int r = 0; r < TJ; ++r) {
        f4 f = fb[r * (H / 4) + h4];
        a0[r] += f.x * w0.x + f.y * w0.y + f.z * w0.z + f.w * w0.w;
        a1[r] += f.x * w1.x + f.y * w1.y + f.z * w1.z + f.w * w1.w;
        a2[r] += f.x * w2.x + f.y * w2.y + f.z * w2.z + f.w * w2.w;
        a3[r] += f.x * w3.x + f.y * w3.y + f.z * w3.z + f.w * w3.w;
      }
    }
    #pragma unroll
    for (int r = 0; r < TJ; ++r)
      rs[r] += __expf(a0[r]) + __expf(a1[r]) + __expf(a2[r]) + __expf(a3[r]);
  }
  if (tid < VC - 1024) {  // tail: 226 rows
    const f4* tt = (const f4*)(term + (size_t)(v0 + 1024 + tid) * H);
    float at[TJ];
    #pragma unroll
    for (int r = 0; r < TJ; ++r) at[r] = 0.f;
    for (int h4 = 0; h4 < H / 4; ++h4) {
      f4 wt = tt[h4];
      #pragma unroll
      for (int r = 0; r < TJ; ++r) {
        f4 f = fb[r * (H / 4) + h4];
        at[r] += f.x * wt.x + f.y * wt.y + f.z * wt.z + f.w * wt.w;
      }
    }
    #pragma unroll
    for (int r = 0; r < TJ; ++r) rs[r] += __expf(at[r]);
  }
  #pragma unroll
  for (int r = 0; r < TJ; ++r) {
    float s = rs[r];
    #pragma unroll
    for (int off = 32; off > 0; off >>= 1) s += __shfl_xor(s, off);
    if (lane == 0) shs[r * 4 + w] = s;
  }
  __syncthreads();
  if (tid < TJ) {
    float s = shs[tid * 4] + shs[tid * 4 + 1] + shs[tid * 4 + 2] + shs[tid * 4 + 3];
    dpart[(jg * TJ + tid) * 8 + vc] = s;
  }
}

// ---------- eem[(t*B+b)*C + j] = exp(ft[j].term[tok] - log(sum dpart[j]) + LV) ----------
__global__ void __launch_bounds__(256) k_eemit(
    const int* __restrict__ text, const float* __restrict__ ft,
    const float* __restrict__ dpart, const float* __restrict__ term,
    float* __restrict__ eem) {
  int tid = threadIdx.x;
  int n0 = blockIdx.x * 8;
  const float4* trow[8];
  #pragma unroll
  for (int r = 0; r < 8; ++r) {
    int n = n0 + r;
    int tok = text[(n & 7) * T + (n >> 3)];  // text[b*T + t], n = t*B+b
    trow[r] = (const float4*)(term + (size_t)tok * H);
  }
  for (int q = 0; q < 4; ++q) {
    int j = q * 256 + tid;
    const float4* fr = (const float4*)(ft + (size_t)j * H);
    float acc[8];
    #pragma unroll
    for (int r = 0; r < 8; ++r) acc[r] = 0.f;
    for (int h4 = 0; h4 < H / 4; ++h4) {
      float4 f = fr[h4];
      #pragma unroll
      for (int r = 0; r < 8; ++r) {
        float4 tv = trow[r][h4];
        acc[r] += f.x * tv.x + f.y * tv.y + f.z * tv.z + f.w * tv.w;
      }
    }
    f4 d0 = *(const f4*)&dpart[j * 8];
    f4 d1 = *(const f4*)&dpart[j * 8 + 4];
    float dj = __logf(d0.x + d0.y + d0.z + d0.w + d1.x + d1.y + d1.z + d1.w);
    #pragma unroll
    for (int r = 0; r < 8; ++r) eem[(size_t)(n0 + r) * C + j] = __expf(acc[r] - dj + LV);
  }
}

// ---------- persistent linear-space scan: sentinel-polled payload ----------
// 256 blocks = 8 batches x 32 blocks. Thread (jloc=tid>>3, s=tid&7) owns
// PT[myj][s*128..+128) loaded ONCE via raw-asm global_load (non-rematerializable
// asm outputs -> compiler must keep them register-resident across the loop).
// Validity of p regs is guaranteed by the poll's s_waitcnt vmcnt(0) before use.
#define PLOADA(k, ofs) \
  asm volatile("global_load_dwordx4 %0, %1, off offset:" #ofs : "=v"(p##k) : "v"(pb));
#define PDOT(k) { f4 x = *(const f4*)&us[ubo + (k) * 4]; facc += p##k * x; }

__global__ void __launch_bounds__(256, 1) k_scan(
    const float* __restrict__ PT, const float* __restrict__ eem,
    const float* __restrict__ startv, float* __restrict__ pay,
    float* __restrict__ umax, float* __restrict__ out) {
  __shared__ __align__(16) float us[8 * 132];  // phys(i) = (i>>7)*132 + (i&127)
  __shared__ float wv[32];
  __shared__ float fred[256];
  const int tid = threadIdx.x, bid = blockIdx.x;
  const int b = bid & 7, blk = bid >> 3;
  const int jloc = tid >> 3, s = tid & 7;
  const int myj = blk * 32 + jloc;
  const bool owner = (s == 0);

  const float* pb = PT + (size_t)myj * C + s * 128;
  f4 p0, p1, p2, p3, p4, p5, p6, p7, p8, p9, p10, p11, p12, p13, p14, p15;
  f4 p16, p17, p18, p19, p20, p21, p22, p23, p24, p25, p26, p27, p28, p29, p30, p31;
  PLOADA(0, 0)    PLOADA(1, 16)   PLOADA(2, 32)   PLOADA(3, 48)
  PLOADA(4, 64)   PLOADA(5, 80)   PLOADA(6, 96)   PLOADA(7, 112)
  PLOADA(8, 128)  PLOADA(9, 144)  PLOADA(10, 160) PLOADA(11, 176)
  PLOADA(12, 192) PLOADA(13, 208) PLOADA(14, 224) PLOADA(15, 240)
  PLOADA(16, 256) PLOADA(17, 272) PLOADA(18, 288) PLOADA(19, 304)
  PLOADA(20, 320) PLOADA(21, 336) PLOADA(22, 352) PLOADA(23, 368)
  PLOADA(24, 384) PLOADA(25, 400) PLOADA(26, 416) PLOADA(27, 432)
  PLOADA(28, 448) PLOADA(29, 464) PLOADA(30, 480) PLOADA(31, 496)

  float Sacc = 0.f;

  // publish u_0 into buf 0 (buffers pre-sentineled by k_pre)
  if (owner) {
    float u0 = __expf(startv[myj]) * eem[(size_t)b * C + myj];
    gstore(&pay[(size_t)b * C + myj], u0);
  }
  float em = owner ? eem[((size_t)B + b) * C + myj] : 0.f;  // prefetch t=1

  const int pi = tid * 4;
  const int ph = (pi >> 7) * 132 + (pi & 127);
  const int ubo = s * 132;

  for (int t = 1; t < T; ++t) {
    // poll+stage u_{t-1}: vmcnt(0) also drains P loads (iter 1) and my clears
    {
      const float* src = pay + (size_t)((t - 1) & 3) * (B * C) + (size_t)b * C + pi;
      f4 r;
      for (;;) {
        asm volatile("global_load_dwordx4 %0, %1, off sc0 sc1\n\ts_waitcnt vmcnt(0)"
                     : "=v"(r) : "v"(src) : "memory");
        unsigned bits = __float_as_uint(r.x) | __float_as_uint(r.y) |
                        __float_as_uint(r.z) | __float_as_uint(r.w);
        if (!(bits & 0x80000000u)) break;
        __builtin_amdgcn_s_sleep(1);
      }
      *(f4*)&us[ph] = r;
    }
    __syncthreads();

    // off-critical-path work first: sentinel-clear buf (t+1)&3 (dead u_{t-3};
    // safe: full u_{t-1} observed => everyone finished reading u_{t-2} and earlier),
    // and prefetch next em. Clears drained by next iteration's poll vmcnt(0),
    // which precedes the barrier that precedes the next publish to that buffer.
    if (tid < 8) {
      float* dst = pay + (size_t)((t + 1) & 3) * (B * C) + (size_t)b * C + blk * 32 + tid * 4;
      f4 sn;
      sn.x = sn.y = sn.z = sn.w = __uint_as_float(SENT);
      asm volatile("global_store_dwordx4 %0, %1, off sc0 sc1" :: "v"(dst), "v"(sn) : "memory");
    }
    float em_next = em;
    if (owner && t + 1 < T) em_next = eem[((size_t)(t + 1) * B + b) * C + myj];

    float imt = 1.f;
    if (owner && (t & 7) == 1 && t > 1) {
      float m = gload(&umax[((t - 1) >> 3) * 8 + b]);
      imt = 1.f / m;
      Sacc += __logf(m);
    }

    // dot over my 128-i slice (P in regs, u from LDS), reduce over 8 s-lanes
    f4 facc = {0.f, 0.f, 0.f, 0.f};
    PDOT(0) PDOT(1) PDOT(2) PDOT(3) PDOT(4) PDOT(5) PDOT(6) PDOT(7)
    PDOT(8) PDOT(9) PDOT(10) PDOT(11) PDOT(12) PDOT(13) PDOT(14) PDOT(15)
    PDOT(16) PDOT(17) PDOT(18) PDOT(19) PDOT(20) PDOT(21) PDOT(22) PDOT(23)
    PDOT(24) PDOT(25) PDOT(26) PDOT(27) PDOT(28) PDOT(29) PDOT(30) PDOT(31)
    float acc = facc.x + facc.y + facc.z + facc.w;
    acc += __shfl_xor(acc, 1);
    acc += __shfl_xor(acc, 2);
    acc += __shfl_xor(acc, 4);

    float val = 0.f;
    if (owner) val = acc * imt * em;

    // sample-max every 8 steps (blk0): umax ordered before tid0's own publish;
    // consumers gate on FULL u_t (incl. tid0's j), so umax is visible when read
    if (blk == 0 && (t & 7) == 0) {
      if (owner) wv[jloc] = val;
      __syncthreads();
      if (tid == 0) {
        float m = wv[0];
        #pragma unroll
        for (int j2 = 1; j2 < 32; ++j2) m = fmaxf(m, wv[j2]);
        gstore(&umax[(t >> 3) * 8 + b], m);
        asm volatile("s_waitcnt vmcnt(0)" ::: "memory");
      }
    }

    // publish u_t
    if (owner) gstore(&pay[(size_t)(t & 3) * (B * C) + (size_t)b * C + myj], val);
    em = em_next;
  }

  // final: block 0 of each batch polls u_{T-1} and reduces
  if (blk == 0) {
    {
      const float* src = pay + (size_t)((T - 1) & 3) * (B * C) + (size_t)b * C + pi;
      f4 r;
      for (;;) {
        asm volatile("global_load_dwordx4 %0, %1, off sc0 sc1\n\ts_waitcnt vmcnt(0)"
                     : "=v"(r) : "v"(src) : "memory");
        unsigned bits = __float_as_uint(r.x) | __float_as_uint(r.y) |
                        __float_as_uint(r.z) | __float_as_uint(r.w);
        if (!(bits & 0x80000000u)) break;
        __builtin_amdgcn_s_sleep(1);
      }
      fred[tid] = r.x + r.y + r.z + r.w;
    }
    __syncthreads();
    for (int off = 128; off > 0; off >>= 1) {
      if (tid < off) fred[tid] += fred[tid + off];
      __syncthreads();
    }
    if (tid == 0) out[b] = -(float)T * LV + Sacc + __logf(fred[0]);
  }
}

extern "C" void kernel_launch(void* const* d_in, const int* in_sizes, int n_in,
                              void* d_out, int out_size, void* d_ws, size_t ws_size,
                              hipStream_t stream) {
  const int*   text  = (const int*)  d_in[0];
  const float* semb  = (const float*)d_in[1];
  const float* slinW = (const float*)d_in[2];
  const float* slinb = (const float*)d_in[3];
  const float* srW1  = (const float*)d_in[4];
  const float* srb1  = (const float*)d_in[5];
  const float* srW2  = (const float*)d_in[6];
  const float* srb2  = (const float*)d_in[7];
  const float* stemb = (const float*)d_in[8];
  const float* nse   = (const float*)d_in[9];
  const float* pre   = (const float*)d_in[10];
  const float* trW1  = (const float*)d_in[11];
  const float* trb1  = (const float*)d_in[12];
  const float* trW2  = (const float*)d_in[13];
  const float* trb2  = (const float*)d_in[14];
  const float* term  = (const float*)d_in[15];
  const float* band  = (const float*)d_in[16];

  float* ws     = (float*)d_ws;
  float* PT     = ws;                          // C*C (transposed P)
  float* eem    = PT + (size_t)C * C;          // T*B*C
  float* pay    = eem + (size_t)T * B * C;     // 4*B*C (4 rotating sentinel buffers)
  float* ftb    = pay + 4 * B * C;             // C*H
  float* startv = ftb + (size_t)C * H;         // C
  float* dpart  = startv + C;                  // C*8 (sum partials)
  float* umax   = dpart + C * 8;               // 32*8

  k_pre<<<529, 256, 0, stream>>>(semb, slinW, slinb, srW1, srb1, srW2, srb2,
                                 nse, stemb, pre, trW1, trb1, trW2, trb2, band,
                                 pay, startv, ftb, PT);
  k_denom_part<<<(C / 16) * 8, 256, 0, stream>>>(ftb, term, dpart);
  k_eemit<<<(T * B) / 8, 256, 0, stream>>>(text, ftb, dpart, term, eem);
  k_scan<<<GSCAN, 256, 0, stream>>>(PT, eem, startv, pay, umax, (float*)d_out);
}

// Round 11
// 857.640 us; speedup vs baseline: 1.3096x; 1.0273x over previous
//
#include <hip/hip_runtime.h>

constexpr int C = 1024, H = 256, V = 10000, K = 32, B = 8, T = 256, K1K = 65;
constexpr int DB = 32;            // blocks per batch domain
constexpr int GSCAN = B * DB;     // 256
constexpr float LV = 9.210340371976184f;  // ln(10000)
constexpr unsigned SENT = 0x80000000u;    // -0.0f: u values are >0, sign bit never set

#define DEV static __device__ __forceinline__

typedef float f4 __attribute__((ext_vector_type(4)));

DEV void gstore(float* p, float v) {
  __hip_atomic_store((unsigned*)p, __float_as_uint(v), __ATOMIC_RELAXED, __HIP_MEMORY_SCOPE_AGENT);
}
DEV float gload(const float* p) {
  return __uint_as_float(__hip_atomic_load((unsigned*)p, __ATOMIC_RELAXED, __HIP_MEMORY_SCOPE_AGENT));
}

// ---------- fused pre-kernel ----------
// bid 0..15: sentinel-init pay; 16: start; 17..80: term MLP (16 rows); 81..208: trans (8 rows)
__global__ void __launch_bounds__(256) k_pre(
    const float* __restrict__ semb, const float* __restrict__ linW, const float* __restrict__ linb,
    const float* __restrict__ srW1, const float* __restrict__ srb1,
    const float* __restrict__ srW2, const float* __restrict__ srb2,
    const float* __restrict__ nse, const float* __restrict__ se,
    const float* __restrict__ pre, const float* __restrict__ trW1, const float* __restrict__ trb1,
    const float* __restrict__ trW2, const float* __restrict__ trb2,
    const float* __restrict__ band,
    float* __restrict__ pay, float* __restrict__ startv,
    float* __restrict__ ft, float* __restrict__ PT) {
  __shared__ float smem[10504];  // 42 KB max across branches
  const int bid = blockIdx.x, tid = threadIdx.x;

  if (bid < 16) {  // sentinel-init 4 payload buffers: 4*B*C dwords
    unsigned* p = (unsigned*)pay;
    #pragma unroll
    for (int k = 0; k < 8; ++k) p[bid * 2048 + k * 256 + tid] = SENT;
    return;
  }

  if (bid == 16) {  // start vector: MLP + log_softmax over C
    float* sa = smem;
    float* fx = smem + 256;
    float* hh = smem + 512;
    float* sl = smem + 768;
    float* red = smem + 1792;
    sa[tid] = semb[tid];
    __syncthreads();
    float acc = linb[tid];
    for (int h = 0; h < H; ++h) acc += sa[h] * linW[tid * H + h];
    fx[tid] = acc;
    __syncthreads();
    for (int l = 0; l < 2; ++l) {
      float a1 = srb1[l * H + tid];
      const float* w1 = srW1 + (size_t)l * H * H + (size_t)tid * H;
      for (int h = 0; h < H; ++h) a1 += fx[h] * w1[h];
      hh[tid] = fmaxf(a1, 0.f);
      __syncthreads();
      float a2 = srb2[l * H + tid];
      const float* w2 = srW2 + (size_t)l * H * H + (size_t)tid * H;
      for (int h = 0; h < H; ++h) a2 += hh[h] * w2[h];
      __syncthreads();
      fx[tid] += fmaxf(a2, 0.f);
      __syncthreads();
    }
    for (int q = 0; q < 4; ++q) {
      int c = q * 256 + tid;
      const float* nr = nse + (size_t)c * H;
      float s = 0.f;
      for (int h = 0; h < H; ++h) s += fx[h] * nr[h];
      sl[c] = s;
    }
    __syncthreads();
    // logits are O(0.1): sum-only logsumexp is exact enough (no max pass)
    float s = 0.f;
    for (int q = 0; q < 4; ++q) s += __expf(sl[q * 256 + tid]);
    red[tid] = s; __syncthreads();
    for (int off = 128; off > 0; off >>= 1) { if (tid < off) red[tid] += red[tid + off]; __syncthreads(); }
    float lse = __logf(red[0]);
    for (int q = 0; q < 4; ++q) { int c = q * 256 + tid; startv[c] = sl[c] - lse; }
    return;
  }

  if (bid < 81) {  // terminal MLP: 16 rows/block (64 blocks) — weights read once per 16 rows
    float* x = smem;          // 16*256
    float* hh = smem + 4096;  // 16*256
    int r0 = (bid - 17) * 16;
    for (int r = 0; r < 16; ++r) x[r * 256 + tid] = pre[(size_t)(r0 + r) * H + tid];
    __syncthreads();
    for (int l = 0; l < 2; ++l) {
      {
        const f4* w = (const f4*)(trW1 + (size_t)l * H * H + (size_t)tid * H);
        float a[16];
        #pragma unroll
        for (int r = 0; r < 16; ++r) a[r] = 0.f;
        for (int h4 = 0; h4 < H / 4; ++h4) {
          f4 wv = w[h4];
          #pragma unroll
          for (int r = 0; r < 16; ++r) {
            f4 xv = *(const f4*)&x[r * 256 + h4 * 4];
            a[r] += wv.x * xv.x + wv.y * xv.y + wv.z * xv.z + wv.w * xv.w;
          }
        }
        float bb = trb1[l * H + tid];
        #pragma unroll
        for (int r = 0; r < 16; ++r) hh[r * 256 + tid] = fmaxf(a[r] + bb, 0.f);
      }
      __syncthreads();
      {
        const f4* w = (const f4*)(trW2 + (size_t)l * H * H + (size_t)tid * H);
        float a[16];
        #pragma unroll
        for (int r = 0; r < 16; ++r) a[r] = 0.f;
        for (int h4 = 0; h4 < H / 4; ++h4) {
          f4 wv = w[h4];
          #pragma unroll
          for (int r = 0; r < 16; ++r) {
            f4 xv = *(const f4*)&hh[r * 256 + h4 * 4];
            a[r] += wv.x * xv.x + wv.y * xv.y + wv.z * xv.z + wv.w * xv.w;
          }
        }
        float bb = trb2[l * H + tid];
        #pragma unroll
        for (int r = 0; r < 16; ++r) x[r * 256 + tid] += fmaxf(a[r] + bb, 0.f);
      }
      __syncthreads();
    }
    for (int r = 0; r < 16; ++r) ft[(size_t)(r0 + r) * H + tid] = x[r * 256 + tid];
    return;
  }

  // transition: 8 rows/block (128 blocks), max-free softmax, packed 32B PT stores
  {
    float* sv = smem;          // 8*256
    float* sl = smem + 2048;   // 8*1024
    float* pr = smem + 10240;  // 256
    float* iv = smem + 10496;  // 8
    int i0 = (bid - 81) * 8;
    for (int r = 0; r < 8; ++r) sv[r * 256 + tid] = se[(size_t)(i0 + r) * H + tid];
    __syncthreads();
    for (int jq = 0; jq < 4; ++jq) {
      int j = jq * 256 + tid;
      const f4* nr = (const f4*)(nse + (size_t)j * H);
      float a[8];
      #pragma unroll
      for (int r = 0; r < 8; ++r) a[r] = 0.f;
      for (int h4 = 0; h4 < H / 4; ++h4) {
        f4 nv = nr[h4];
        #pragma unroll
        for (int r = 0; r < 8; ++r) {
          f4 s4 = *(const f4*)&sv[r * 256 + h4 * 4];
          a[r] += nv.x * s4.x + nv.y * s4.y + nv.z * s4.z + nv.w * s4.w;
        }
      }
      #pragma unroll
      for (int r = 0; r < 8; ++r) sl[r * 1024 + j] = a[r];
    }
    __syncthreads();
    if (tid < K1K) {
      #pragma unroll
      for (int r = 0; r < 8; ++r) {
        int col = i0 + r + tid - K;
        if (col >= 0 && col < C) sl[r * 1024 + col] += band[(size_t)(i0 + r) * K1K + tid];
      }
    }
    __syncthreads();
    {  // exp + parallel row sums (logits O(0.1): no max needed)
      int row = tid >> 5, lane32 = tid & 31;
      float s = 0.f;
      for (int k = 0; k < 32; ++k) {
        int idx = row * 1024 + lane32 + k * 32;
        float e = __expf(sl[idx]);
        sl[idx] = e;
        s += e;
      }
      pr[tid] = s;
    }
    __syncthreads();
    if (tid < 8) {
      float s = 0.f;
      for (int k = 0; k < 32; ++k) s += pr[tid * 32 + k];
      iv[tid] = 1.f / s;
    }
    __syncthreads();
    for (int jq = 0; jq < 4; ++jq) {
      int j = jq * 256 + tid;
      f4 o0, o1;
      o0.x = sl[0 * 1024 + j] * iv[0]; o0.y = sl[1 * 1024 + j] * iv[1];
      o0.z = sl[2 * 1024 + j] * iv[2]; o0.w = sl[3 * 1024 + j] * iv[3];
      o1.x = sl[4 * 1024 + j] * iv[4]; o1.y = sl[5 * 1024 + j] * iv[5];
      o1.z = sl[6 * 1024 + j] * iv[6]; o1.w = sl[7 * 1024 + j] * iv[7];
      f4* dst = (f4*)(PT + (size_t)j * C + i0);
      dst[0] = o0; dst[1] = o1;  // 32B contiguous per thread
    }
  }
}

// ---------- emission denominators: sum-only, v-unrolled x4 (r8, proven) ----------
__global__ void __launch_bounds__(256) k_denom_part(
    const float* __restrict__ ft, const float* __restrict__ term, float* __restrict__ dpart) {
  constexpr int TJ = 16, VC = V / 8;  // 1250 = 4*256 + 226
  __shared__ float shs[TJ * 4];
  int tid = threadIdx.x, lane = tid & 63, w = tid >> 6;
  int jg = blockIdx.x >> 3, vc = blockIdx.x & 7;
  const f4* fb = (const f4*)(ft + (size_t)jg * TJ * H);
  float rs[TJ];
  #pragma unroll
  for (int r = 0; r < TJ; ++r) rs[r] = 0.f;
  int v0 = vc * VC;
  {
    const f4* t0 = (const f4*)(term + (size_t)(v0 + tid) * H);
    const f4* t1 = t0 + 256 * (H / 4);
    const f4* t2 = t1 + 256 * (H / 4);
    const f4* t3 = t2 + 256 * (H / 4);
    float a0[TJ], a1[TJ], a2[TJ], a3[TJ];
    #pragma unroll
    for (int r = 0; r < TJ; ++r) { a0[r] = 0.f; a1[r] = 0.f; a2[r] = 0.f; a3[r] = 0.f; }
    for (int h4 = 0; h4 < H / 4; ++h4) {
      f4 w0 = t0[h4], w1 = t1[h4], w2 = t2[h4], w3 = t3[h4];
      #pragma unroll
      for (int r = 0; r < TJ; ++r) {
        f4 f = fb[r * (H / 4) + h4];
        a0[r] += f.x * w0.x + f.y * w0.y + f.z * w0.z + f.w * w0.w;
        a1[r] += f.x * w1.x + f.y * w1.y + f.z * w1.z + f.w * w1.w;
        a2[r] += f.x * w2.x + f.y * w2.y + f.z * w2.z + f.w * w2.w;
        a3[r] += f.x * w3.x + f.y * w3.y + f.z * w3.z + f.w * w3.w;
      }
    }
    #pragma unroll
    for (int r = 0; r < TJ; ++r)
      rs[r] += __expf(a0[r]) + __expf(a1[r]) + __expf(a2[r]) + __expf(a3[r]);
  }
  if (tid < VC - 1024) {
    const f4* tt = (const f4*)(term + (size_t)(v0 + 1024 + tid) * H);
    float at[TJ];
    #pragma unroll
    for (int r = 0; r < TJ; ++r) at[r] = 0.f;
    for (int h4 = 0; h4 < H / 4; ++h4) {
      f4 wt = tt[h4];
      #pragma unroll
      for (int r = 0; r < TJ; ++r) {
        f4 f = fb[r * (H / 4) + h4];
        at[r] += f.x * wt.x + f.y * wt.y + f.z * wt.z + f.w * wt.w;
      }
    }
    #pragma unroll
    for (int r = 0; r < TJ; ++r) rs[r] += __expf(at[r]);
  }
  #pragma unroll
  for (int r = 0; r < TJ; ++r) {
    float s = rs[r];
    #pragma unroll
    for (int off = 32; off > 0; off >>= 1) s += __shfl_xor(s, off);
    if (lane == 0) shs[r * 4 + w] = s;
  }
  __syncthreads();
  if (tid < TJ) {
    float s = shs[tid * 4] + shs[tid * 4 + 1] + shs[tid * 4 + 2] + shs[tid * 4 + 3];
    dpart[(jg * TJ + tid) * 8 + vc] = s;
  }
}

// ---------- eem: 32 tokens/block staged in LDS, 512 j per block (128 blocks) ----------
__global__ void __launch_bounds__(256) k_eemit(
    const int* __restrict__ text, const float* __restrict__ ft,
    const float* __restrict__ dpart, const float* __restrict__ term,
    float* __restrict__ eem) {
  __shared__ float tk[32 * 256];  // 32 KB token rows
  __shared__ int ids[32];
  const int tid = threadIdx.x, bid = blockIdx.x;
  const int n0 = (bid >> 1) * 32, jh = bid & 1;
  if (tid < 32) {
    int n = n0 + tid;
    ids[tid] = text[(n & 7) * T + (n >> 3)];  // text[b*T + t], n = t*B+b
  }
  __syncthreads();
  for (int r = 0; r < 32; ++r) tk[r * 256 + tid] = term[(size_t)ids[r] * H + tid];
  __syncthreads();
  for (int q = 0; q < 2; ++q) {
    int j = jh * 512 + q * 256 + tid;
    const f4* fr = (const f4*)(ft + (size_t)j * H);
    float acc[32];
    #pragma unroll
    for (int r = 0; r < 32; ++r) acc[r] = 0.f;
    for (int h4 = 0; h4 < H / 4; ++h4) {
      f4 fv = fr[h4];
      #pragma unroll
      for (int r = 0; r < 32; ++r) {
        f4 tv = *(const f4*)&tk[r * 256 + h4 * 4];
        acc[r] += fv.x * tv.x + fv.y * tv.y + fv.z * tv.z + fv.w * tv.w;
      }
    }
    f4 d0 = *(const f4*)&dpart[j * 8];
    f4 d1 = *(const f4*)&dpart[j * 8 + 4];
    float dj = __logf(d0.x + d0.y + d0.z + d0.w + d1.x + d1.y + d1.z + d1.w);
    #pragma unroll
    for (int r = 0; r < 32; ++r)
      eem[(size_t)(n0 + r) * C + j] = __expf(acc[r] - dj + LV);
  }
}

// ---------- persistent scan: bid-based domains (r8 proven), packed publish,
// clears retargeted to buf (t+2)&3 with a 2-step safety margin ----------
#define PLOADA(k, ofs) \
  asm volatile("global_load_dwordx4 %0, %1, off offset:" #ofs : "=v"(p##k) : "v"(pb));
#define PDOT(k) { f4 x = *(const f4*)&us[ubo + (k) * 4]; facc += p##k * x; }

__global__ void __launch_bounds__(256, 1) k_scan(
    const float* __restrict__ PT, const float* __restrict__ eem,
    const float* __restrict__ startv, float* __restrict__ pay,
    float* __restrict__ umax, float* __restrict__ out) {
  __shared__ __align__(16) float us[8 * 132];  // phys(i) = (i>>7)*132 + (i&127)
  __shared__ __align__(16) float wv[32];
  __shared__ float fred[256];
  const int tid = threadIdx.x, bid = blockIdx.x;
  const int b = bid & 7, blk = bid >> 3;
  const int jloc = tid >> 3, s = tid & 7;
  const int myj = blk * 32 + jloc;
  const bool owner = (s == 0);

  // P slice via raw asm loads (validity enforced by first poll's vmcnt(0))
  const float* pb = PT + (size_t)myj * C + s * 128;
  f4 p0, p1, p2, p3, p4, p5, p6, p7, p8, p9, p10, p11, p12, p13, p14, p15;
  f4 p16, p17, p18, p19, p20, p21, p22, p23, p24, p25, p26, p27, p28, p29, p30, p31;
  PLOADA(0, 0)    PLOADA(1, 16)   PLOADA(2, 32)   PLOADA(3, 48)
  PLOADA(4, 64)   PLOADA(5, 80)   PLOADA(6, 96)   PLOADA(7, 112)
  PLOADA(8, 128)  PLOADA(9, 144)  PLOADA(10, 160) PLOADA(11, 176)
  PLOADA(12, 192) PLOADA(13, 208) PLOADA(14, 224) PLOADA(15, 240)
  PLOADA(16, 256) PLOADA(17, 272) PLOADA(18, 288) PLOADA(19, 304)
  PLOADA(20, 320) PLOADA(21, 336) PLOADA(22, 352) PLOADA(23, 368)
  PLOADA(24, 384) PLOADA(25, 400) PLOADA(26, 416) PLOADA(27, 432)
  PLOADA(28, 448) PLOADA(29, 464) PLOADA(30, 480) PLOADA(31, 496)

  float Sacc = 0.f;

  // publish u_0 into buf 0 (sentinels from k_pre)
  if (owner) {
    float u0 = __expf(startv[myj]) * eem[(size_t)b * C + myj];
    gstore(&pay[(size_t)b * C + myj], u0);
  }
  float em = owner ? eem[((size_t)B + b) * C + myj] : 0.f;  // prefetch t=1

  const int pi = tid * 4;
  const int ph = (pi >> 7) * 132 + (pi & 127);
  const int ubo = s * 132;

  for (int t = 1; t < T; ++t) {
    // poll+stage u_{t-1}: vmcnt(0) drains P loads (iter1), my clears, my publishes
    {
      const float* src = pay + (size_t)((t - 1) & 3) * (B * C) + (size_t)b * C + pi;
      f4 r;
      for (;;) {
        asm volatile("global_load_dwordx4 %0, %1, off sc0 sc1\n\ts_waitcnt vmcnt(0)"
                     : "=v"(r) : "v"(src) : "memory");
        unsigned bits = __float_as_uint(r.x) | __float_as_uint(r.y) |
                        __float_as_uint(r.z) | __float_as_uint(r.w);
        if (!(bits & 0x80000000u)) break;
        __builtin_amdgcn_s_sleep(1);
      }
      *(f4*)&us[ph] = r;
    }
    __syncthreads();

    float em_next = em;
    if (owner && t + 1 < T) em_next = eem[((size_t)(t + 1) * B + b) * C + myj];

    float imt = 1.f;
    if (owner && (t & 7) == 1 && t > 1) {
      float m = gload(&umax[((t - 1) >> 3) * 8 + b]);
      imt = 1.f / m;
      Sacc += __logf(m);
    }

    // dot over my 128-i slice (u in LDS), reduce over 8 s-lanes
    f4 facc = {0.f, 0.f, 0.f, 0.f};
    PDOT(0) PDOT(1) PDOT(2) PDOT(3) PDOT(4) PDOT(5) PDOT(6) PDOT(7)
    PDOT(8) PDOT(9) PDOT(10) PDOT(11) PDOT(12) PDOT(13) PDOT(14) PDOT(15)
    PDOT(16) PDOT(17) PDOT(18) PDOT(19) PDOT(20) PDOT(21) PDOT(22) PDOT(23)
    PDOT(24) PDOT(25) PDOT(26) PDOT(27) PDOT(28) PDOT(29) PDOT(30) PDOT(31)
    float acc = facc.x + facc.y + facc.z + facc.w;
    acc += __shfl_xor(acc, 1);
    acc += __shfl_xor(acc, 2);
    acc += __shfl_xor(acc, 4);

    if (owner) wv[jloc] = acc * imt * em;
    __syncthreads();

    // sample-max every 8 steps (blk0): umax drained before this block's publish;
    // consumers gate on FULL u_t, so umax is visible when read at t+1
    if (blk == 0 && (t & 7) == 0) {
      if (tid == 0) {
        float m = wv[0];
        #pragma unroll
        for (int j2 = 1; j2 < 32; ++j2) m = fmaxf(m, wv[j2]);
        gstore(&umax[(t >> 3) * 8 + b], m);
        asm volatile("s_waitcnt vmcnt(0)" ::: "memory");
      }
      __syncthreads();
    }

    // packed publish: 8 lanes store the block's 128B chunk as dwordx4 granules
    if (tid < 8) {
      f4 pv4 = *(const f4*)&wv[tid * 4];
      float* dst = pay + (size_t)(t & 3) * (B * C) + (size_t)b * C + blk * 32 + tid * 4;
      asm volatile("global_store_dwordx4 %0, %1, off sc0 sc1" :: "v"(dst), "v"(pv4) : "memory");
    }

    // sentinel-clear buf (t+2)&3 (holds u_{t-2}: provably consumed by all since
    // full u_{t-1} was observed). 2-step margin before u_{t+2} publishes land here;
    // this block's own re-publish into it is ordered by two poll vmcnt(0)s.
    if (tid < 8) {
      float* dst = pay + (size_t)((t + 2) & 3) * (B * C) + (size_t)b * C + blk * 32 + tid * 4;
      f4 sn;
      sn.x = sn.y = sn.z = sn.w = __uint_as_float(SENT);
      asm volatile("global_store_dwordx4 %0, %1, off sc0 sc1" :: "v"(dst), "v"(sn) : "memory");
    }
    em = em_next;
  }

  // final: block 0 of each batch polls u_{T-1} and reduces
  if (blk == 0) {
    {
      const float* src = pay + (size_t)((T - 1) & 3) * (B * C) + (size_t)b * C + pi;
      f4 r;
      for (;;) {
        asm volatile("global_load_dwordx4 %0, %1, off sc0 sc1\n\ts_waitcnt vmcnt(0)"
                     : "=v"(r) : "v"(src) : "memory");
        unsigned bits = __float_as_uint(r.x) | __float_as_uint(r.y) |
                        __float_as_uint(r.z) | __float_as_uint(r.w);
        if (!(bits & 0x80000000u)) break;
        __builtin_amdgcn_s_sleep(1);
      }
      fred[tid] = r.x + r.y + r.z + r.w;
    }
    __syncthreads();
    for (int off = 128; off > 0; off >>= 1) {
      if (tid < off) fred[tid] += fred[tid + off];
      __syncthreads();
    }
    if (tid == 0) out[b] = -(float)T * LV + Sacc + __logf(fred[0]);
  }
}

extern "C" void kernel_launch(void* const* d_in, const int* in_sizes, int n_in,
                              void* d_out, int out_size, void* d_ws, size_t ws_size,
                              hipStream_t stream) {
  const int*   text  = (const int*)  d_in[0];
  const float* semb  = (const float*)d_in[1];
  const float* slinW = (const float*)d_in[2];
  const float* slinb = (const float*)d_in[3];
  const float* srW1  = (const float*)d_in[4];
  const float* srb1  = (const float*)d_in[5];
  const float* srW2  = (const float*)d_in[6];
  const float* srb2  = (const float*)d_in[7];
  const float* stemb = (const float*)d_in[8];
  const float* nse   = (const float*)d_in[9];
  const float* pre   = (const float*)d_in[10];
  const float* trW1  = (const float*)d_in[11];
  const float* trb1  = (const float*)d_in[12];
  const float* trW2  = (const float*)d_in[13];
  const float* trb2  = (const float*)d_in[14];
  const float* term  = (const float*)d_in[15];
  const float* band  = (const float*)d_in[16];

  float* ws     = (float*)d_ws;
  float* PT     = ws;                          // C*C (transposed P, fp32)
  float* eem    = PT + (size_t)C * C;          // T*B*C
  float* pay    = eem + (size_t)T * B * C;     // 4*B*C rotating sentinel buffers
  float* ftb    = pay + 4 * B * C;             // C*H
  float* startv = ftb + (size_t)C * H;         // C
  float* dpart  = startv + C;                  // C*8
  float* umax   = dpart + C * 8;               // 32*8

  k_pre<<<209, 256, 0, stream>>>(semb, slinW, slinb, srW1, srb1, srW2, srb2,
                                 nse, stemb, pre, trW1, trb1, trW2, trb2, band,
                                 pay, startv, ftb, PT);
  k_denom_part<<<(C / 16) * 8, 256, 0, stream>>>(ftb, term, dpart);
  k_eemit<<<128, 256, 0, stream>>>(text, ftb, dpart, term, eem);  // 64 tok-groups x 2 j-halves
  k_scan<<<GSCAN, 256, 0, stream>>>(PT, eem, startv, pay, umax, (float*)d_out);
}